// Round 9
// baseline (261.896 us; speedup 1.0000x reference)
//
#include <hip/hip_runtime.h>
#include <float.h>

typedef __bf16 bf16x8 __attribute__((ext_vector_type(8)));
typedef __bf16 bf16x4 __attribute__((ext_vector_type(4)));
typedef float  f32x4  __attribute__((ext_vector_type(4)));

#define G      256
#define MT     32      // points per tile (R4 config — best measured)
#define H1DIM  64
#define H2DIM  128
#define LAT    256
#define H1PAD  72      // 144 B rows: 16B-aligned, 36 dw == 4 mod 32 -> 2-way (free) b128
#define H2PAD  136     // 272 B rows: 16B-aligned, 68 dw == 4 mod 32 -> 2-way (free) b128

// order-preserving float->uint map: max on uints == max on floats
__device__ __forceinline__ unsigned mapf(float f) {
  unsigned u = __float_as_uint(f);
  return (u & 0x80000000u) ? ~u : (u | 0x80000000u);
}
__device__ __forceinline__ float unmapf(unsigned u) {
  return (u & 0x80000000u) ? __uint_as_float(u & 0x7fffffffu) : __uint_as_float(~u);
}

// flush helper: vectors BY VALUE (no address-taken -> no scratch).
// Reduces over the 16 point-lanes, adds bias, atomicMax to global pooled[s].
__device__ __forceinline__ void flush4(f32x4 v0, f32x4 v1, f32x4 v2, f32x4 v3,
                                       int s, int w, int q, int nn,
                                       const float* __restrict__ b3,
                                       unsigned* __restrict__ pooled) {
  f32x4 vv[4] = {v0, v1, v2, v3};
  #pragma unroll
  for (int mt = 0; mt < 4; ++mt)
    #pragma unroll
    for (int r = 0; r < 4; ++r) {
      int feat = w * 64 + mt * 16 + q * 4 + r;
      float v = vv[mt][r] + b3[feat];
      v = fmaxf(v, __shfl_xor(v, 1));
      v = fmaxf(v, __shfl_xor(v, 2));
      v = fmaxf(v, __shfl_xor(v, 4));
      v = fmaxf(v, __shfl_xor(v, 8));
      if (nn == 0) atomicMax(&pooled[s * LAT + feat], mapf(v));
    }
}

// ---------------- fused centroid + MLP + segment max ----------------
// R4 structure (MT=32, 4 waves, 155us) with ~30 VALU-live regs moved to LDS so
// (256,3) fits WITHOUT cap-squeeze spilling:
//   - w2f fragments in LDS cache (lane-contiguous 16B slots, conflict-free b128)
//   - run[4] segment-max state in per-thread LDS slots shRun[4][256]
//   - b1 folded into W1 k=4 row (1.0 input slot); b2 in LDS; centroid in LDS
// Estimated AGPR ~100 (w3f+w1f+acc) + VGPR ~60 -> ~160 total <= 168 cap.
__global__ __launch_bounds__(256, 3) void mlp_kernel(
    const float* __restrict__ pc,
    const float* __restrict__ W1, const float* __restrict__ b1,
    const float* __restrict__ W2, const float* __restrict__ b2,
    const float* __restrict__ W3, const float* __restrict__ b3,
    const int* __restrict__ sid,
    unsigned* __restrict__ pooled,
    float* __restrict__ sums,
    int n, int tiles_per_block) {
  __shared__ __align__(16) __bf16 shF[MT][8];
  __shared__ __align__(16) __bf16 sh1[MT][H1PAD];
  __shared__ __align__(16) __bf16 sh2[MT][H2PAD];
  __shared__ int   segt[MT];
  __shared__ __align__(16) float  shB2[H2DIM];     // staged b2
  __shared__ float shC[MT][5];                     // centroid acc (stride 5)
  __shared__ int   shCseg[MT];
  __shared__ __align__(16) bf16x8 shW2[16 * 64];   // w2f frag cache: [(w*4+f)*64+lane]
  __shared__ __align__(16) f32x4  shRun[4][256];   // per-thread running max slots

  const int t  = threadIdx.x;
  const int w  = t >> 6;         // wave id 0..3
  const int lane = t & 63;
  const int q  = lane >> 4;
  const int nn = lane & 15;

  // ---- persistent weight fragments (A-operand: A[m=nn][k=q*8+j]) ----
  bf16x8 w1f;                    // L1, K=32 zero-padded; k=4 row carries b1
  #pragma unroll
  for (int j = 0; j < 8; ++j) {
    int k = q * 8 + j;
    float wv = (k < 4) ? W1[k * H1DIM + w * 16 + nn]
             : (k == 4 ? b1[w * 16 + nn] : 0.f);
    w1f[j] = (__bf16)wv;
  }

  // w2 fragments -> LDS cache (not registers)
  #pragma unroll
  for (int mt = 0; mt < 2; ++mt) {
    int m = w * 32 + mt * 16 + nn;
    #pragma unroll
    for (int ks = 0; ks < 2; ++ks) {
      bf16x8 f;
      #pragma unroll
      for (int j = 0; j < 8; ++j)
        f[j] = (__bf16)W2[(ks * 32 + q * 8 + j) * H2DIM + m];
      shW2[(w * 4 + mt * 2 + ks) * 64 + lane] = f;
    }
  }

  bf16x8 w3f[4][4];              // [mt][ks] -- stays in registers (AGPR-eligible)
  #pragma unroll
  for (int mt = 0; mt < 4; ++mt) {
    int m = w * 64 + mt * 16 + nn;
    #pragma unroll
    for (int ks = 0; ks < 4; ++ks)
      #pragma unroll
      for (int j = 0; j < 8; ++j)
        w3f[mt][ks][j] = (__bf16)W3[(ks * 32 + q * 8 + j) * LAT + m];
  }

  const f32x4 zero4 = {0.f, 0.f, 0.f, 0.f};
  const bf16x8 zero8 = {};
  const f32x4 neginf4 = {-FLT_MAX, -FLT_MAX, -FLT_MAX, -FLT_MAX};

  if (t < H2DIM) shB2[t] = b2[t];
  if (t < MT) { shCseg[t] = -1; shC[t][0] = 0.f; shC[t][1] = 0.f; shC[t][2] = 0.f; shC[t][3] = 0.f; }
  #pragma unroll
  for (int mt = 0; mt < 4; ++mt) shRun[mt][t] = neginf4;

  const int tile0 = blockIdx.x * tiles_per_block;
  int first = tile0 * MT; if (first > n - 1) first = n - 1;
  int s_cur = sid[first];

  for (int ti = 0; ti < tiles_per_block; ++ti) {
    const int base = (tile0 + ti) * MT;
    if (base >= n) break;

    // ---- stage 32 points (clamped duplicates are harmless for max) ----
    if (t < MT) {
      int p = base + t;
      bool valid = p < n;
      int pcl = valid ? p : (n - 1);
      const float* pp = pc + (size_t)pcl * 5;
      float fx = pp[4], p1 = pp[1], p2 = pp[2], p3 = pp[3];
      bf16x8 v = {};
      v[0] = (__bf16)fx;   // x first (concat order!)
      v[1] = (__bf16)p1;
      v[2] = (__bf16)p2;
      v[3] = (__bf16)p3;
      v[4] = (__bf16)1.0f; // bias slot: picks up b1 from W1 row k=4
      *reinterpret_cast<bf16x8*>(&shF[t][0]) = v;
      int s = sid[pcl];
      segt[t] = s;
      if (valid) {
        int pseg = shCseg[t];
        if (s != pseg) {
          float pcnt = shC[t][3];
          if (pcnt > 0.f) {
            atomicAdd(&sums[pseg * 4 + 0], shC[t][0]);
            atomicAdd(&sums[pseg * 4 + 1], shC[t][1]);
            atomicAdd(&sums[pseg * 4 + 2], shC[t][2]);
            atomicAdd(&sums[pseg * 4 + 3], pcnt);
          }
          shCseg[t] = s;
          shC[t][0] = p1; shC[t][1] = p2; shC[t][2] = p3; shC[t][3] = 1.f;
        } else {
          shC[t][0] += p1; shC[t][1] += p2; shC[t][2] += p3; shC[t][3] += 1.f;
        }
      }
    }
    __syncthreads();

    // ---- layer 1 (MFMA, K zero-padded; bias folded) ----
    {
      f32x4 acc1[2];
      #pragma unroll
      for (int nt = 0; nt < 2; ++nt) {
        bf16x8 ld = *reinterpret_cast<const bf16x8*>(&shF[nt * 16 + nn][0]);
        bf16x8 af = (q == 0) ? ld : zero8;
        acc1[nt] = __builtin_amdgcn_mfma_f32_16x16x32_bf16(w1f, af, zero4, 0, 0, 0);
      }
      #pragma unroll
      for (int nt = 0; nt < 2; ++nt) {
        bf16x4 pk;
        #pragma unroll
        for (int r = 0; r < 4; ++r)
          pk[r] = (__bf16)fmaxf(acc1[nt][r], 0.f);
        *reinterpret_cast<bf16x4*>(&sh1[nt * 16 + nn][w * 16 + q * 4]) = pk;
      }
    }
    __syncthreads();

    // ---- layer 2: (32x64) @ (64x128); w2 frags from LDS cache ----
    {
      f32x4 acc2[2][2];
      #pragma unroll
      for (int mt = 0; mt < 2; ++mt)
        #pragma unroll
        for (int nt = 0; nt < 2; ++nt) acc2[mt][nt] = zero4;
      #pragma unroll
      for (int ks = 0; ks < 2; ++ks) {
        bf16x8 bfr[2];
        #pragma unroll
        for (int nt = 0; nt < 2; ++nt)
          bfr[nt] = *reinterpret_cast<const bf16x8*>(&sh1[nt * 16 + nn][ks * 32 + q * 8]);
        #pragma unroll
        for (int mt = 0; mt < 2; ++mt) {
          bf16x8 w2frag = shW2[(w * 4 + mt * 2 + ks) * 64 + lane];
          #pragma unroll
          for (int nt = 0; nt < 2; ++nt)
            acc2[mt][nt] = __builtin_amdgcn_mfma_f32_16x16x32_bf16(w2frag, bfr[nt], acc2[mt][nt], 0, 0, 0);
        }
      }
      #pragma unroll
      for (int mt = 0; mt < 2; ++mt) {
        f32x4 b2v = *reinterpret_cast<const f32x4*>(&shB2[w * 32 + mt * 16 + q * 4]);
        #pragma unroll
        for (int nt = 0; nt < 2; ++nt) {
          bf16x4 pk;
          #pragma unroll
          for (int r = 0; r < 4; ++r)
            pk[r] = (__bf16)fmaxf(acc2[mt][nt][r] + b2v[r], 0.f);
          *reinterpret_cast<bf16x4*>(&sh2[nt * 16 + nn][w * 32 + mt * 16 + q * 4]) = pk;
        }
      }
    }
    __syncthreads();

    // ---- layer 3: (32x128) @ (128x256) ----
    f32x4 acc3[4][2];
    #pragma unroll
    for (int mt = 0; mt < 4; ++mt)
      #pragma unroll
      for (int nt = 0; nt < 2; ++nt) acc3[mt][nt] = zero4;
    #pragma unroll
    for (int ks = 0; ks < 4; ++ks) {
      bf16x8 bfr[2];
      #pragma unroll
      for (int nt = 0; nt < 2; ++nt)
        bfr[nt] = *reinterpret_cast<const bf16x8*>(&sh2[nt * 16 + nn][ks * 32 + q * 8]);
      #pragma unroll
      for (int mt = 0; mt < 4; ++mt)
        #pragma unroll
        for (int nt = 0; nt < 2; ++nt)
          acc3[mt][nt] = __builtin_amdgcn_mfma_f32_16x16x32_bf16(w3f[mt][ks], bfr[nt], acc3[mt][nt], 0, 0, 0);
    }

    // ---- segment max (sorted ids; block-uniform control); run state in LDS ----
    int smin = segt[0], smax = segt[MT - 1];
    if (smin == smax && smin == s_cur) {
      // fast path: whole tile continues current segment
      #pragma unroll
      for (int mt = 0; mt < 4; ++mt) {
        f32x4 rt = shRun[mt][t];
        #pragma unroll
        for (int r = 0; r < 4; ++r)
          rt[r] = fmaxf(rt[r], fmaxf(acc3[mt][0][r], acc3[mt][1][r]));
        shRun[mt][t] = rt;
      }
    } else {
      // general path (segment transitions; rare)
      f32x4 rt0 = shRun[0][t], rt1 = shRun[1][t], rt2 = shRun[2][t], rt3 = shRun[3][t];
      if (smin != s_cur) {          // previous segment ended exactly at tile edge
        flush4(rt0, rt1, rt2, rt3, s_cur, w, q, nn, b3, pooled);
        rt0 = neginf4; rt1 = neginf4; rt2 = neginf4; rt3 = neginf4;
        s_cur = smin;
      }
      if (smin == smax) {
        #pragma unroll
        for (int r = 0; r < 4; ++r) {
          rt0[r] = fmaxf(rt0[r], fmaxf(acc3[0][0][r], acc3[0][1][r]));
          rt1[r] = fmaxf(rt1[r], fmaxf(acc3[1][0][r], acc3[1][1][r]));
          rt2[r] = fmaxf(rt2[r], fmaxf(acc3[2][0][r], acc3[2][1][r]));
          rt3[r] = fmaxf(rt3[r], fmaxf(acc3[3][0][r], acc3[3][1][r]));
        }
      } else {
        int sg0 = segt[nn], sg1 = segt[16 + nn];
        for (int s = smin; s <= smax; ++s) {
          f32x4 tmp[4];
          #pragma unroll
          for (int mt = 0; mt < 4; ++mt)
            #pragma unroll
            for (int r = 0; r < 4; ++r) {
              float v0 = (sg0 == s) ? acc3[mt][0][r] : -FLT_MAX;
              float v1 = (sg1 == s) ? acc3[mt][1][r] : -FLT_MAX;
              tmp[mt][r] = fmaxf(v0, v1);
            }
          if (s < smax) {
            if (s == s_cur) {
              #pragma unroll
              for (int r = 0; r < 4; ++r) {
                rt0[r] = fmaxf(rt0[r], tmp[0][r]);
                rt1[r] = fmaxf(rt1[r], tmp[1][r]);
                rt2[r] = fmaxf(rt2[r], tmp[2][r]);
                rt3[r] = fmaxf(rt3[r], tmp[3][r]);
              }
              flush4(rt0, rt1, rt2, rt3, s, w, q, nn, b3, pooled);
              rt0 = neginf4; rt1 = neginf4; rt2 = neginf4; rt3 = neginf4;
            } else {
              flush4(tmp[0], tmp[1], tmp[2], tmp[3], s, w, q, nn, b3, pooled);
            }
          } else {
            #pragma unroll
            for (int r = 0; r < 4; ++r) {
              rt0[r] = fmaxf(rt0[r], tmp[0][r]);
              rt1[r] = fmaxf(rt1[r], tmp[1][r]);
              rt2[r] = fmaxf(rt2[r], tmp[2][r]);
              rt3[r] = fmaxf(rt3[r], tmp[3][r]);
            }
          }
        }
        s_cur = smax;
      }
      shRun[0][t] = rt0; shRun[1][t] = rt1; shRun[2][t] = rt2; shRun[3][t] = rt3;
    }
    __syncthreads();   // protect shF/segt/sh1/sh2 against next iteration's writes
  }
  {
    f32x4 rt0 = shRun[0][t], rt1 = shRun[1][t], rt2 = shRun[2][t], rt3 = shRun[3][t];
    flush4(rt0, rt1, rt2, rt3, s_cur, w, q, nn, b3, pooled);
  }

  // final centroid flush
  if (t < MT) {
    int pseg = shCseg[t];
    float pcnt = shC[t][3];
    if (pseg >= 0 && pcnt > 0.f) {
      atomicAdd(&sums[pseg * 4 + 0], shC[t][0]);
      atomicAdd(&sums[pseg * 4 + 1], shC[t][1]);
      atomicAdd(&sums[pseg * 4 + 2], shC[t][2]);
      atomicAdd(&sums[pseg * 4 + 3], pcnt);
    }
  }
}

// ---------------- head: pooled @ Wf + bf -> softplus, + centroid ----------------
__global__ void final_kernel(const float* __restrict__ sums, const unsigned* __restrict__ pooled,
                             const float* __restrict__ Wf, const float* __restrict__ bfv,
                             float* __restrict__ out) {
  __shared__ float red[4][3];
  int g = blockIdx.x;
  int t = threadIdx.x;   // 256 = LAT
  unsigned u = pooled[g * LAT + t];
  float f = u ? unmapf(u) : 0.f;
  float s0 = f * Wf[t * 3 + 0];
  float s1 = f * Wf[t * 3 + 1];
  float s2 = f * Wf[t * 3 + 2];
  #pragma unroll
  for (int off = 1; off < 64; off <<= 1) {
    s0 += __shfl_xor(s0, off);
    s1 += __shfl_xor(s1, off);
    s2 += __shfl_xor(s2, off);
  }
  int wave = t >> 6;
  if ((t & 63) == 0) { red[wave][0] = s0; red[wave][1] = s1; red[wave][2] = s2; }
  __syncthreads();
  if (t < 3) {
    float acc = bfv[t] + red[0][t] + red[1][t] + red[2][t] + red[3][t];
    float sp  = fmaxf(acc, 0.f) + log1pf(expf(-fabsf(acc)));
    float cnt = fmaxf(sums[g * 4 + 3], 1.f);
    float cen = sums[g * 4 + t] / cnt;
    out[g * 3 + t] = cen + sp;
  }
}

extern "C" void kernel_launch(void* const* d_in, const int* in_sizes, int n_in,
                              void* d_out, int out_size, void* d_ws, size_t ws_size,
                              hipStream_t stream) {
  const float* pc  = (const float*)d_in[0];
  const float* W1  = (const float*)d_in[1];
  const float* b1  = (const float*)d_in[2];
  const float* W2  = (const float*)d_in[3];
  const float* b2  = (const float*)d_in[4];
  const float* W3  = (const float*)d_in[5];
  const float* b3  = (const float*)d_in[6];
  const float* Wf  = (const float*)d_in[7];
  const float* bfv = (const float*)d_in[8];
  const int*   sid = (const int*)d_in[9];
  int n = in_sizes[0] / 5;

  float*    sums   = (float*)d_ws;                         // G*4 fp32
  unsigned* pooled = (unsigned*)((char*)d_ws + 4096);      // G*LAT mapped-uint maxes
  hipMemsetAsync(d_ws, 0, 4096 + (size_t)G * LAT * 4, stream);

  int tiles   = (n + MT - 1) / MT;
  int nblocks = 768;                         // 3 blocks/CU at __launch_bounds__(256,3)
  int tpb     = (tiles + nblocks - 1) / nblocks;
  mlp_kernel<<<nblocks, 256, 0, stream>>>(pc, W1, b1, W2, b2, W3, b3, sid, pooled, sums, n, tpb);

  final_kernel<<<G, 256, 0, stream>>>(sums, pooled, Wf, bfv, (float*)d_out);
}